// Round 14
// baseline (105.020 us; speedup 1.0000x reference)
//
#include <hip/hip_runtime.h>

// LSTM: B=16384, T=1024, I=1, H=2, C=4.
// 2 lanes per batch element: lane (2e+j) owns hidden unit j of element e.
//
// R14 = R13 (91.7 us: R10 body + 4-deep x prefetch pipeline) with the
// h-path collapsed from THREE serial trans stages to TWO:
//   exp2 -> rcp(B) -> rcp(D)   ==>   exp2 -> rcp(Bm*Q*Oo)
// via HOMOGENEOUS Pade[5/4]: tanh(A/B)*sigma(o) = zA*P(a,b)*rcp(Bm*Q(a,b)*Oo),
//   a = zA^2, b = Bm^2, P = a^2+105ab+945b^2, Q = 15a^2+420ab+945b^2.
// KEY FIX vs R8 (which tried this and regressed): the cell carry stays
//   c = A * rcp(B)  — a PARALLEL rcp OFF the h-critical-path (consumed only
// at next step's cp = c*Ip, ~140 cy slack), NOT routed through the final
// rcp like R8 did. Trans issue count unchanged (4 exp2 + 2 rcp).
// B (up to ~1e9) is normalized to Bm in [1,2) by the exponent-only bit
// hack (exact powers of 2): prevents 945*b^2 overflow; At/Bm == A/B.
// Clamp zA = med3(At, -4Bm, 4Bm) == |c'|<=4, identical to R10.
//
// Gate rows (PyTorch order): i: 0,1  f: 2,3  g: 4,5  o: 6,7
//   Ei=e^-i, Ef=e^-f, Eo=e^-o (SIG_SCALE folded), Eg=e^{2g} (TANH_SCALE).
//   c' = A/B:  A = (c*Ip)*Gp + (Eg-1)*F,  B = (Gp*F)*Ip,
//   F=1+Ef, Ip=1+Ei, Gp=1+Eg, Oo=1+Eo.

typedef float f32x2 __attribute__((ext_vector_type(2)));

static __device__ __forceinline__ float fast_exp2(float x) { return __builtin_amdgcn_exp2f(x); }
static __device__ __forceinline__ float fast_rcp(float x)  { return __builtin_amdgcn_rcpf(x); }

// Swap values between lane pairs (0<->1, 2<->3, ...) via DPP quad_perm.
static __device__ __forceinline__ float dpp_swap1(float v) {
    int i = __builtin_bit_cast(int, v);
    i = __builtin_amdgcn_mov_dpp(i, 0xB1, 0xF, 0xF, false);
    return __builtin_bit_cast(float, i);
}

#define SIG_SCALE  (-1.4426950408889634f)  // -log2(e)
#define TANH_SCALE ( 2.8853900817779268f)  // 2*log2(e)

__global__ __launch_bounds__(64, 1) void lstm_fused10(
    const float* __restrict__ x,      // [B, T, 1]
    const float* __restrict__ W_ih,   // [8, 1]
    const float* __restrict__ W_hh,   // [8, 2]
    const float* __restrict__ b_ih,   // [8]
    const float* __restrict__ b_hh,   // [8]
    const float* __restrict__ W_fc,   // [4, 2]
    const float* __restrict__ b_fc,   // [4]
    float* __restrict__ out,          // [B, 4]
    int T)
{
    const int tid = blockIdx.x * 64 + threadIdx.x;
    const int e   = tid >> 1;          // batch element
    const int j   = tid & 1;           // hidden unit owned by this lane

    // Per-lane scaled weights for my unit's 4 gates (k: 0=i,1=f,2=g,3=o).
    // whm multiplies MY h, whp multiplies my PARTNER's h.
    float wihs[4], whm[4], whp[4], bbs[4];
#pragma unroll
    for (int k = 0; k < 4; ++k) {
        const int g = 2 * k + j;                         // gate row
        const float s = (k == 2) ? TANH_SCALE : SIG_SCALE;
        wihs[k] = s * W_ih[g];
        whm[k]  = s * W_hh[2 * g + j];
        whp[k]  = s * W_hh[2 * g + (j ^ 1)];
        bbs[k]  = s * (b_ih[g] + b_hh[g]);
    }

    // Packed views for v_pk_fma_f32 on the pre-activation math.
    f32x2 wihs2[2], whm2[2], whp2[2], bbs2[2];
#pragma unroll
    for (int q = 0; q < 2; ++q) {
        wihs2[q] = f32x2{wihs[2*q], wihs[2*q+1]};
        whm2[q]  = f32x2{whm[2*q],  whm[2*q+1]};
        whp2[q]  = f32x2{whp[2*q],  whp[2*q+1]};
        bbs2[q]  = f32x2{bbs[2*q],  bbs[2*q+1]};
    }

    float hm = 0.f;   // my unit's h
    float hp = 0.f;   // partner unit's h
    float c  = 0.f;   // my unit's c

    const float4* xv = reinterpret_cast<const float4*>(x + (size_t)e * (size_t)T);
    const int nt4 = T >> 2;            // 256 groups of 4 timesteps

    // 4-deep rotating prefetch pipeline (static slots — no dynamic indexing).
    float4 slot0 = xv[0];
    float4 slot1 = xv[1];
    float4 slot2 = xv[2];
    float4 slot3 = xv[3];

    const int nblk = nt4 >> 2;         // 64 blocks of 4 groups

    for (int bg = 0; bg < nblk; ++bg) {
        const int g0 = bg << 2;

#pragma unroll
        for (int i = 0; i < 4; ++i) {
            // Consume slot i (group g0+i), then re-issue its load for
            // group g0+i+4 (clamped): ~12 steps in flight > HBM latency.
            float4 xq = (i == 0) ? slot0 : (i == 1) ? slot1 : (i == 2) ? slot2 : slot3;

            const int gn = g0 + i + 4;
            const int gl = (gn < nt4) ? gn : (nt4 - 1);    // uniform clamp
            const float4 nx = xv[gl];
            if (i == 0) slot0 = nx; else if (i == 1) slot1 = nx;
            else if (i == 2) slot2 = nx; else slot3 = nx;

            const float xs[4] = {xq.x, xq.y, xq.z, xq.w};

            // h-independent x-terms for 4 timesteps (packed fma, off-chain).
            f32x2 xterm[4][2];
#pragma unroll
            for (int u = 0; u < 4; ++u) {
                const f32x2 xu = f32x2{xs[u], xs[u]};
#pragma unroll
                for (int q = 0; q < 2; ++q)
                    xterm[u][q] = __builtin_elementwise_fma(xu, wihs2[q], bbs2[q]);
            }

#pragma unroll
            for (int u = 0; u < 4; ++u) {
                const f32x2 hmv = f32x2{hm, hm};
                const f32x2 hpv = f32x2{hp, hp};
                // pre23 first: Eg (pre23.x) heads the critical path.
                const f32x2 pre23 = __builtin_elementwise_fma(
                    whm2[1], hmv, __builtin_elementwise_fma(whp2[1], hpv, xterm[u][1]));
                const f32x2 pre01 = __builtin_elementwise_fma(
                    whm2[0], hmv, __builtin_elementwise_fma(whp2[0], hpv, xterm[u][0]));

                // Chain-critical exps first: Eg, Ef, Ei; Eo has slack.
                const float Eg = fast_exp2(pre23.x);
                const float Ef = fast_exp2(pre01.y);
                const float Ei = fast_exp2(pre01.x);
                const float Eo = fast_exp2(pre23.y);

                const float Gp  = 1.f + Eg;
                const float F   = 1.f + Ef;
                const float Ip  = 1.f + Ei;
                const float Oo  = 1.f + Eo;

                const float GpF = Gp * F;
                const float GmF = fmaf(Eg, F, -F);             // (Eg-1)(1+Ef)
                const float B   = GpF * Ip;
                const float cp  = c * Ip;
                const float A   = fmaf(cp, Gp, GmF);

                // Cell carry: parallel rcp, OFF the h-critical-path
                // (consumed next step at cp, ~140 cy slack).
                const float rB = fast_rcp(B);
                c = A * rB;

                // Exponent-only normalization: Bm in [1,2), At/Bm == A/B.
                const unsigned Bi = __builtin_bit_cast(unsigned, B);
                const float Bm = __builtin_bit_cast(float,
                                    (Bi & 0x007FFFFFu) | 0x3F800000u);
                const float sc = __builtin_bit_cast(float,
                                    0x7F000000u - (Bi & 0x7F800000u));
                const float At = A * sc;

                // Clamp |A/B| <= 4 in normalized space.
                const float B4 = 4.0f * Bm;
                const float zA = __builtin_amdgcn_fmed3f(At, -B4, B4);

                // Homogeneous Pade[5/4]: tanh(zA/Bm)*sigma(o) in ONE rcp.
                const float a  = zA * zA;
                const float b  = Bm * Bm;
                const float b2 = b * b;
                const float u9 = 945.f * b2;

                const float t1 = fmaf(105.f, b, a);
                const float P  = fmaf(t1, a, u9);              // a^2+105ab+945b^2
                const float t2 = 420.f * b;
                const float q1 = fmaf(15.f, a, t2);
                const float Q  = fmaf(q1, a, u9);              // 15a^2+420ab+945b^2

                const float BmOo = Bm * Oo;
                const float den  = BmOo * Q;
                const float rD   = fast_rcp(den);              // trans stage 2 (h-path)
                const float numer = zA * P;                    // issues during rcp
                hm = numer * rD;                               // tanh(c')*sigma(o)

                hp = dpp_swap1(hm);                            // lane-pair swap
            }
        }
    }

    // Final FC: out[e,:] = h @ W_fc^T + b_fc.  Even lane -> classes 0,1;
    // odd lane -> classes 2,3. Lane pair writes one contiguous 16B row.
    const float h0 = j ? hp : hm;
    const float h1 = j ? hm : hp;
    const int   c0 = 2 * j;
    const float o0 = fmaf(W_fc[2*c0+0], h0, fmaf(W_fc[2*c0+1], h1, b_fc[c0]));
    const float o1 = fmaf(W_fc[2*c0+2], h0, fmaf(W_fc[2*c0+3], h1, b_fc[c0+1]));
    float2 r2; r2.x = o0; r2.y = o1;
    reinterpret_cast<float2*>(out)[e * 2 + j] = r2;
}

extern "C" void kernel_launch(void* const* d_in, const int* in_sizes, int n_in,
                              void* d_out, int out_size, void* d_ws, size_t ws_size,
                              hipStream_t stream) {
    const float* x    = (const float*)d_in[0];
    const float* W_ih = (const float*)d_in[1];
    const float* W_hh = (const float*)d_in[2];
    const float* b_ih = (const float*)d_in[3];
    const float* b_hh = (const float*)d_in[4];
    const float* W_fc = (const float*)d_in[5];
    const float* b_fc = (const float*)d_in[6];
    float* out = (float*)d_out;

    const int T = 1024;
    const int B = in_sizes[0] / T;   // I == 1

    dim3 block(64);
    dim3 grid((B * 2) / 64);         // 512 waves -> 2 waves/CU (R10 placement)
    lstm_fused10<<<grid, block, 0, stream>>>(x, W_ih, W_hh, b_ih, b_hh, W_fc, b_fc, out, T);
}

// Round 15
// 87.995 us; speedup vs baseline: 1.1935x; 1.1935x over previous
//
#include <hip/hip_runtime.h>

// LSTM: B=16384, T=1024, I=1, H=2, C=4.
// 2 lanes per batch element: lane (2e+j) owns hidden unit j of element e.
//
// R15 = R13 (verified best: 91.7 us = 215 cy/step) + ISSUE-COUNT packing.
// Cost model (refit R5-R14): solo in-order wave => wall = issue + unhidden
// stalls = ~129 + ~86 cy/step. Instruction count dominates; so this round
// only REMOVES instructions, never adds (R8/R11/R14 all regressed by
// trading 1 trans for ~9 VALU):
//  1. (1+E) adds packed: 2x v_pk_add_f32 instead of 4 scalar adds.
//  2. Pade[5/4] p,q polys packed with coeff vectors {1,15},{105,420},{945}:
//     2x v_pk_fma_f32 instead of add+3 fma.
//  3. pre = fma(whp, hp, fma(whm, hm, xterm)): hm-term issues before the
//     DPP delivers hp (-4 cy chain).
// Memory path (4-deep rotating prefetch), exp2 ordering, clamp-before-rcp,
// placement: all byte-identical to R13.
//
// Gate rows (PyTorch order): i: 0,1  f: 2,3  g: 4,5  o: 6,7
//   Ei=e^-i, Ef=e^-f, Eo=e^-o (SIG_SCALE folded), Eg=e^{2g} (TANH_SCALE).
//   c' = A/B:  A = (c*Ip)*Gp + (Eg-1)*F,  B = (Gp*F)*Ip,
//   F=1+Ef, Ip=1+Ei, Gp=1+Eg, Oo=1+Eo.
//   h' = tanh(zc)*sigma(o), zc = med3(A,-4B,4B)*rB,
//   tanh(zc) = zc*(zc^4+105zc^2+945)/(15zc^4+420zc^2+945),  D = q*Oo.

typedef float f32x2 __attribute__((ext_vector_type(2)));

static __device__ __forceinline__ float fast_exp2(float x) { return __builtin_amdgcn_exp2f(x); }
static __device__ __forceinline__ float fast_rcp(float x)  { return __builtin_amdgcn_rcpf(x); }

// Swap values between lane pairs (0<->1, 2<->3, ...) via DPP quad_perm.
static __device__ __forceinline__ float dpp_swap1(float v) {
    int i = __builtin_bit_cast(int, v);
    i = __builtin_amdgcn_mov_dpp(i, 0xB1, 0xF, 0xF, false);
    return __builtin_bit_cast(float, i);
}

#define SIG_SCALE  (-1.4426950408889634f)  // -log2(e)
#define TANH_SCALE ( 2.8853900817779268f)  // 2*log2(e)

__global__ __launch_bounds__(64, 1) void lstm_fused11(
    const float* __restrict__ x,      // [B, T, 1]
    const float* __restrict__ W_ih,   // [8, 1]
    const float* __restrict__ W_hh,   // [8, 2]
    const float* __restrict__ b_ih,   // [8]
    const float* __restrict__ b_hh,   // [8]
    const float* __restrict__ W_fc,   // [4, 2]
    const float* __restrict__ b_fc,   // [4]
    float* __restrict__ out,          // [B, 4]
    int T)
{
    const int tid = blockIdx.x * 64 + threadIdx.x;
    const int e   = tid >> 1;          // batch element
    const int j   = tid & 1;           // hidden unit owned by this lane

    // Per-lane scaled weights for my unit's 4 gates (k: 0=i,1=f,2=g,3=o).
    // whm multiplies MY h, whp multiplies my PARTNER's h.
    float wihs[4], whm[4], whp[4], bbs[4];
#pragma unroll
    for (int k = 0; k < 4; ++k) {
        const int g = 2 * k + j;                         // gate row
        const float s = (k == 2) ? TANH_SCALE : SIG_SCALE;
        wihs[k] = s * W_ih[g];
        whm[k]  = s * W_hh[2 * g + j];
        whp[k]  = s * W_hh[2 * g + (j ^ 1)];
        bbs[k]  = s * (b_ih[g] + b_hh[g]);
    }

    // Packed views for v_pk_fma_f32 on the pre-activation math.
    f32x2 wihs2[2], whm2[2], whp2[2], bbs2[2];
#pragma unroll
    for (int q = 0; q < 2; ++q) {
        wihs2[q] = f32x2{wihs[2*q], wihs[2*q+1]};
        whm2[q]  = f32x2{whm[2*q],  whm[2*q+1]};
        whp2[q]  = f32x2{whp[2*q],  whp[2*q+1]};
        bbs2[q]  = f32x2{bbs[2*q],  bbs[2*q+1]};
    }

    // Hoisted VOP3P constant vectors (loop-invariant registers).
    const f32x2 one2    = {1.f, 1.f};
    const f32x2 pq_hi   = {1.f, 15.f};     // leading coeffs of p,q
    const f32x2 pq_mid  = {105.f, 420.f};  // middle coeffs
    const f32x2 pq_lo   = {945.f, 945.f};  // constant terms

    float hm = 0.f;   // my unit's h
    float hp = 0.f;   // partner unit's h
    float c  = 0.f;   // my unit's c

    const float4* xv = reinterpret_cast<const float4*>(x + (size_t)e * (size_t)T);
    const int nt4 = T >> 2;            // 256 groups of 4 timesteps

    // 4-deep rotating prefetch pipeline (static slots — no dynamic indexing).
    float4 slot0 = xv[0];
    float4 slot1 = xv[1];
    float4 slot2 = xv[2];
    float4 slot3 = xv[3];

    const int nblk = nt4 >> 2;         // 64 blocks of 4 groups

    for (int bg = 0; bg < nblk; ++bg) {
        const int g0 = bg << 2;

#pragma unroll
        for (int i = 0; i < 4; ++i) {
            // Consume slot i (group g0+i), then re-issue its load for
            // group g0+i+4 (clamped): ~12 steps in flight > HBM latency.
            float4 xq = (i == 0) ? slot0 : (i == 1) ? slot1 : (i == 2) ? slot2 : slot3;

            const int gn = g0 + i + 4;
            const int gl = (gn < nt4) ? gn : (nt4 - 1);    // uniform clamp
            const float4 nx = xv[gl];
            if (i == 0) slot0 = nx; else if (i == 1) slot1 = nx;
            else if (i == 2) slot2 = nx; else slot3 = nx;

            const float xs[4] = {xq.x, xq.y, xq.z, xq.w};

            // h-independent x-terms for 4 timesteps (packed fma, off-chain).
            f32x2 xterm[4][2];
#pragma unroll
            for (int u = 0; u < 4; ++u) {
                const f32x2 xu = f32x2{xs[u], xs[u]};
#pragma unroll
                for (int q = 0; q < 2; ++q)
                    xterm[u][q] = __builtin_elementwise_fma(xu, wihs2[q], bbs2[q]);
            }

#pragma unroll
            for (int u = 0; u < 4; ++u) {
                const f32x2 hmv = f32x2{hm, hm};
                const f32x2 hpv = f32x2{hp, hp};
                // hm-term first (hm ready before DPP delivers hp).
                const f32x2 in23 = __builtin_elementwise_fma(whm2[1], hmv, xterm[u][1]);
                const f32x2 in01 = __builtin_elementwise_fma(whm2[0], hmv, xterm[u][0]);
                const f32x2 pre23 = __builtin_elementwise_fma(whp2[1], hpv, in23);
                const f32x2 pre01 = __builtin_elementwise_fma(whp2[0], hpv, in01);

                // Chain-critical exps first: Eg, Ef, Ei; Eo has slack.
                const float Eg = fast_exp2(pre23.x);
                const float Ef = fast_exp2(pre01.y);
                const float Ei = fast_exp2(pre01.x);
                const float Eo = fast_exp2(pre23.y);

                // Packed (1+E): E01={Ei,Ef}, E23={Eg,Eo}.
                const f32x2 E01 = {Ei, Ef};
                const f32x2 E23 = {Eg, Eo};
                const f32x2 P01 = E01 + one2;   // {Ip, F}
                const f32x2 P23 = E23 + one2;   // {Gp, Oo}
                const float Ip = P01.x, F = P01.y, Gp = P23.x, Oo = P23.y;

                const float GpF = Gp * F;
                const float GmF = fmaf(Eg, F, -F);             // (Eg-1)(1+Ef)
                const float B   = GpF * Ip;
                const float cp  = c * Ip;
                const float A   = fmaf(cp, Gp, GmF);

                // Clamp in (A,B) space BEFORE the rcp (issues during rcp wait).
                const float B4  = 4.0f * B;
                const float zA  = __builtin_amdgcn_fmed3f(A, -B4, B4);

                const float rB  = fast_rcp(B);                 // trans stage 2
                c = A * rB;                                    // next cell, off-path
                const float zc = zA * rB;                      // clamped c'

                // Pade[5/4] tanh, p & q packed: {p,q} in 2 pk_fma.
                const float uu = zc * zc;
                const f32x2 uu2 = {uu, uu};
                const f32x2 pq_in = __builtin_elementwise_fma(pq_hi, uu2, pq_mid);
                const f32x2 pq    = __builtin_elementwise_fma(pq_in, uu2, pq_lo);

                const float numer = zc * pq.x;
                const float D  = pq.y * Oo;
                const float rD = fast_rcp(D);                  // trans stage 3
                hm = numer * rD;                               // tanh(c')*sigma(o)

                hp = dpp_swap1(hm);                            // lane-pair swap
            }
        }
    }

    // Final FC: out[e,:] = h @ W_fc^T + b_fc.  Even lane -> classes 0,1;
    // odd lane -> classes 2,3. Lane pair writes one contiguous 16B row.
    const float h0 = j ? hp : hm;
    const float h1 = j ? hm : hp;
    const int   c0 = 2 * j;
    const float o0 = fmaf(W_fc[2*c0+0], h0, fmaf(W_fc[2*c0+1], h1, b_fc[c0]));
    const float o1 = fmaf(W_fc[2*c0+2], h0, fmaf(W_fc[2*c0+3], h1, b_fc[c0+1]));
    float2 r2; r2.x = o0; r2.y = o1;
    reinterpret_cast<float2*>(out)[e * 2 + j] = r2;
}

extern "C" void kernel_launch(void* const* d_in, const int* in_sizes, int n_in,
                              void* d_out, int out_size, void* d_ws, size_t ws_size,
                              hipStream_t stream) {
    const float* x    = (const float*)d_in[0];
    const float* W_ih = (const float*)d_in[1];
    const float* W_hh = (const float*)d_in[2];
    const float* b_ih = (const float*)d_in[3];
    const float* b_hh = (const float*)d_in[4];
    const float* W_fc = (const float*)d_in[5];
    const float* b_fc = (const float*)d_in[6];
    float* out = (float*)d_out;

    const int T = 1024;
    const int B = in_sizes[0] / T;   // I == 1

    dim3 block(64);
    dim3 grid((B * 2) / 64);         // 512 waves -> 2 waves/CU (R10 placement)
    lstm_fused11<<<grid, block, 0, stream>>>(x, W_ih, W_hh, b_ih, b_hh, W_fc, b_fc, out, T);
}